// Round 2
// baseline (315.627 us; speedup 1.0000x reference)
//
#include <hip/hip_runtime.h>
#include <hip/hip_bf16.h>

typedef unsigned short u16;
typedef __attribute__((ext_vector_type(8))) short short8;
typedef __attribute__((ext_vector_type(4))) float floatx4;

// Problem constants
#define NH     16
#define DHEAD  64
#define NSEQ   2048
#define DMODEL 1024
#define NBATCH 2
#define MTOT   (NBATCH * NSEQ)   // 4096

__device__ inline u16 f2bf(float f) {
    unsigned int u = __builtin_bit_cast(unsigned int, f);
    unsigned int rounding = 0x7FFFu + ((u >> 16) & 1u);
    return (u16)((u + rounding) >> 16);
}

// Load 8 contiguous elements as bf16x8 (converting if fp32 source).
__device__ inline short8 ld8(const float* p) {
    floatx4 a = *(const floatx4*)p;
    floatx4 b = *(const floatx4*)(p + 4);
    short8 r;
    r[0] = (short)f2bf(a[0]); r[1] = (short)f2bf(a[1]);
    r[2] = (short)f2bf(a[2]); r[3] = (short)f2bf(a[3]);
    r[4] = (short)f2bf(b[0]); r[5] = (short)f2bf(b[1]);
    r[6] = (short)f2bf(b[2]); r[7] = (short)f2bf(b[3]);
    return r;
}
__device__ inline short8 ld8(const u16* p) {
    return *(const short8*)p;
}

// ---------------------------------------------------------------------------
// GEMM: C = A (MxK) * B^T (B is NxK row-major) [+ bias], bf16 MFMA, fp32 acc.
// M = 4096, N = 1024, K = 1024. Block tile 64x64, BK=64, 4 waves of 32x32.
// MODE 0: float C[row*1024 + col] + bias        (final projection, fp32 out)
// MODE 1: bf16 C[((b*16+h)*2048+tok)*64 + d]    (Q/K layout [b,h,n,dh])
// MODE 2: bf16 C[((b*16+h)*64+d)*2048 + tok]    (V^T layout [b,h,dh,n])
// ---------------------------------------------------------------------------
template <int MODE, typename TA, typename TB>
__global__ __launch_bounds__(256) void gemm_bt(const TA* __restrict__ A,
                                               const TB* __restrict__ B,
                                               const float* __restrict__ bias,
                                               void* __restrict__ Cv)
{
    __shared__ __align__(16) short As[64][72];
    __shared__ __align__(16) short Bs[64][72];

    const int tid  = threadIdx.x;
    const int w    = tid >> 6;          // wave 0..3
    const int lane = tid & 63;
    const int ln   = lane & 15;
    const int q    = lane >> 4;         // quad 0..3
    const int wm   = w >> 1;            // wave row 0..1
    const int wn   = w & 1;             // wave col 0..1
    const int m0   = blockIdx.y * 64;
    const int n0   = blockIdx.x * 64;
    const int r    = tid >> 3;          // 0..31 staging row
    const int c8   = (tid & 7) * 8;     // staging col group

    floatx4 zero = {0.f, 0.f, 0.f, 0.f};
    floatx4 acc[2][2];
    acc[0][0] = zero; acc[0][1] = zero; acc[1][0] = zero; acc[1][1] = zero;

    for (int k0 = 0; k0 < DMODEL; k0 += 64) {
        *(short8*)&As[r][c8]      = ld8(&A[(size_t)(m0 + r) * DMODEL + k0 + c8]);
        *(short8*)&As[r + 32][c8] = ld8(&A[(size_t)(m0 + r + 32) * DMODEL + k0 + c8]);
        *(short8*)&Bs[r][c8]      = ld8(&B[(size_t)(n0 + r) * DMODEL + k0 + c8]);
        *(short8*)&Bs[r + 32][c8] = ld8(&B[(size_t)(n0 + r + 32) * DMODEL + k0 + c8]);
        __syncthreads();
#pragma unroll
        for (int kk = 0; kk < 2; ++kk) {
            short8 a0 = *(short8*)&As[wm * 32 + ln][kk * 32 + q * 8];
            short8 a1 = *(short8*)&As[wm * 32 + 16 + ln][kk * 32 + q * 8];
            short8 b0 = *(short8*)&Bs[wn * 32 + ln][kk * 32 + q * 8];
            short8 b1 = *(short8*)&Bs[wn * 32 + 16 + ln][kk * 32 + q * 8];
            acc[0][0] = __builtin_amdgcn_mfma_f32_16x16x32_bf16(a0, b0, acc[0][0], 0, 0, 0);
            acc[0][1] = __builtin_amdgcn_mfma_f32_16x16x32_bf16(a0, b1, acc[0][1], 0, 0, 0);
            acc[1][0] = __builtin_amdgcn_mfma_f32_16x16x32_bf16(a1, b0, acc[1][0], 0, 0, 0);
            acc[1][1] = __builtin_amdgcn_mfma_f32_16x16x32_bf16(a1, b1, acc[1][1], 0, 0, 0);
        }
        __syncthreads();
    }

#pragma unroll
    for (int mt = 0; mt < 2; ++mt) {
#pragma unroll
        for (int nt = 0; nt < 2; ++nt) {
            const int coln = wn * 32 + nt * 16 + ln;   // col within 64-tile
            float bval = 0.f;
            if (MODE == 0) bval = bias[n0 + coln];
#pragma unroll
            for (int reg = 0; reg < 4; ++reg) {
                const int rowm = wm * 32 + mt * 16 + q * 4 + reg;  // row within 64-tile
                const int grow = m0 + rowm;                        // global row (token)
                const float v = acc[mt][nt][reg] + bval;
                if (MODE == 0) {
                    ((float*)Cv)[(size_t)grow * DMODEL + n0 + coln] = v;
                } else {
                    const int b   = grow >> 11;        // /2048
                    const int tok = grow & 2047;
                    const int h   = n0 >> 6;           // N-tile == head (64 == dh)
                    if (MODE == 1)
                        ((u16*)Cv)[((size_t)(b * NH + h) * NSEQ + tok) * DHEAD + coln] = f2bf(v);
                    else
                        ((u16*)Cv)[((size_t)(b * NH + h) * DHEAD + coln) * NSEQ + tok] = f2bf(v);
                }
            }
        }
    }
}

// ---------------------------------------------------------------------------
// Flash attention: Q [b,h,n,dh], K [b,h,n,dh], Vt [b,h,dh,n] -> O [b,n,h*dh]
// All bf16. Block: (qtile, bh). 4 waves x 16 Q-rows. K/V tiles of 64.
// ---------------------------------------------------------------------------
__global__ __launch_bounds__(256) void attn_kernel(const u16* __restrict__ Q,
                                                   const u16* __restrict__ K,
                                                   const u16* __restrict__ Vt,
                                                   u16* __restrict__ O)
{
    __shared__ __align__(16) short Ks[64][72];   // [j][d]
    __shared__ __align__(16) short Vs[64][72];   // [d][j]
    __shared__ __align__(16) short Ps[4][16][72];// per-wave P [i][j]

    const int tid  = threadIdx.x;
    const int w    = tid >> 6;
    const int lane = tid & 63;
    const int ln   = lane & 15;
    const int q    = lane >> 4;
    const int bh   = blockIdx.y;            // 0..31
    const int qt   = blockIdx.x;            // 0..31
    const int qbase = qt * 64;
    const int r    = tid >> 3;              // staging row 0..31
    const int c8   = (tid & 7) * 8;

    // Load this wave's Q fragments once (reused across all K tiles)
    const u16* qptr = Q + ((size_t)bh * NSEQ + qbase + w * 16 + ln) * DHEAD;
    short8 aq[2];
    aq[0] = *(const short8*)&qptr[q * 8];
    aq[1] = *(const short8*)&qptr[32 + q * 8];

    floatx4 zero = {0.f, 0.f, 0.f, 0.f};
    floatx4 o[4];
    float mrow[4], lrow[4];
#pragma unroll
    for (int i = 0; i < 4; ++i) { o[i] = zero; mrow[i] = -INFINITY; lrow[i] = 0.f; }

    for (int kt = 0; kt < NSEQ / 64; ++kt) {
        const int kbase = kt * 64;
        *(short8*)&Ks[r][c8]      = *(const short8*)&K[((size_t)bh * NSEQ + kbase + r) * DHEAD + c8];
        *(short8*)&Ks[r + 32][c8] = *(const short8*)&K[((size_t)bh * NSEQ + kbase + r + 32) * DHEAD + c8];
        *(short8*)&Vs[r][c8]      = *(const short8*)&Vt[((size_t)bh * DHEAD + r) * NSEQ + kbase + c8];
        *(short8*)&Vs[r + 32][c8] = *(const short8*)&Vt[((size_t)bh * DHEAD + r + 32) * NSEQ + kbase + c8];
        __syncthreads();

        // S = Q * K^T (this wave's 16 rows x 64 cols)
        floatx4 s[4];
#pragma unroll
        for (int t = 0; t < 4; ++t) {
            s[t] = zero;
#pragma unroll
            for (int kk = 0; kk < 2; ++kk) {
                short8 bk = *(short8*)&Ks[t * 16 + ln][kk * 32 + q * 8];
                s[t] = __builtin_amdgcn_mfma_f32_16x16x32_bf16(aq[kk], bk, s[t], 0, 0, 0);
            }
        }

        // Online softmax per row (row = q*4 + reg, cols spread over 16 lanes x 4 frags)
#pragma unroll
        for (int reg = 0; reg < 4; ++reg) {
            float mx = -INFINITY;
#pragma unroll
            for (int t = 0; t < 4; ++t) {
                s[t][reg] *= 0.125f;                // scale = dh^-0.5
                mx = fmaxf(mx, s[t][reg]);
            }
#pragma unroll
            for (int off = 1; off < 16; off <<= 1)
                mx = fmaxf(mx, __shfl_xor(mx, off, 64));
            const float mnew  = fmaxf(mrow[reg], mx);
            const float alpha = __expf(mrow[reg] - mnew);
            float rs = 0.f;
#pragma unroll
            for (int t = 0; t < 4; ++t) {
                float p = __expf(s[t][reg] - mnew);
                s[t][reg] = p;
                rs += p;
            }
#pragma unroll
            for (int off = 1; off < 16; off <<= 1)
                rs += __shfl_xor(rs, off, 64);
            lrow[reg] = lrow[reg] * alpha + rs;
            mrow[reg] = mnew;
#pragma unroll
            for (int t = 0; t < 4; ++t) {
                o[t][reg] *= alpha;
                Ps[w][q * 4 + reg][t * 16 + ln] = (short)f2bf(s[t][reg]);
            }
        }

        // O += P * V   (P via LDS round-trip into A-layout; Vt gives contiguous B reads)
        short8 pf0 = *(short8*)&Ps[w][ln][q * 8];
        short8 pf1 = *(short8*)&Ps[w][ln][32 + q * 8];
#pragma unroll
        for (int t = 0; t < 4; ++t) {
            short8 bv0 = *(short8*)&Vs[t * 16 + ln][q * 8];
            short8 bv1 = *(short8*)&Vs[t * 16 + ln][32 + q * 8];
            o[t] = __builtin_amdgcn_mfma_f32_16x16x32_bf16(pf0, bv0, o[t], 0, 0, 0);
            o[t] = __builtin_amdgcn_mfma_f32_16x16x32_bf16(pf1, bv1, o[t], 0, 0, 0);
        }
        __syncthreads();
    }

    // Write O in [b, n, h*dh] layout for the final projection GEMM
    const int b = bh >> 4, h = bh & 15;
#pragma unroll
    for (int t = 0; t < 4; ++t) {
#pragma unroll
        for (int reg = 0; reg < 4; ++reg) {
            const int tok = qbase + w * 16 + q * 4 + reg;
            const float v = o[t][reg] / lrow[reg];
            O[((size_t)(b * NSEQ + tok)) * DMODEL + h * DHEAD + t * 16 + ln] = f2bf(v);
        }
    }
}

// ---------------------------------------------------------------------------
extern "C" void kernel_launch(void* const* d_in, const int* in_sizes, int n_in,
                              void* d_out, int out_size, void* d_ws, size_t ws_size,
                              hipStream_t stream) {
    (void)in_sizes; (void)n_in; (void)out_size; (void)ws_size;
    const float* x  = (const float*)d_in[0];
    const float* Wq = (const float*)d_in[1];
    const float* Wk = (const float*)d_in[2];
    const float* Wv = (const float*)d_in[3];
    const float* Wo = (const float*)d_in[4];
    const float* bo = (const float*)d_in[5];
    float* out = (float*)d_out;

    const size_t tsz = (size_t)MTOT * DMODEL;  // 4096*1024 elements (bf16)
    u16* Qb  = (u16*)d_ws;
    u16* Kb  = Qb + tsz;
    u16* Vtb = Kb + tsz;
    u16* Ob  = Vtb + tsz;

    dim3 gg(DMODEL / 64, MTOT / 64);  // (16, 64)
    dim3 bb(256);
    gemm_bt<1, float, float><<<gg, bb, 0, stream>>>(x, Wq, nullptr, Qb);
    gemm_bt<1, float, float><<<gg, bb, 0, stream>>>(x, Wk, nullptr, Kb);
    gemm_bt<2, float, float><<<gg, bb, 0, stream>>>(x, Wv, nullptr, Vtb);

    dim3 ga(NSEQ / 64, NBATCH * NH);  // (32, 32)
    attn_kernel<<<ga, bb, 0, stream>>>(Qb, Kb, Vtb, Ob);

    gemm_bt<0, u16, float><<<gg, bb, 0, stream>>>(Ob, Wo, bo, out);
}

// Round 3
// 275.214 us; speedup vs baseline: 1.1468x; 1.1468x over previous
//
#include <hip/hip_runtime.h>
#include <hip/hip_bf16.h>

typedef unsigned short u16;
typedef __attribute__((ext_vector_type(8))) short short8;
typedef __attribute__((ext_vector_type(4))) float floatx4;

#define NH     16
#define DHEAD  64
#define NSEQ   2048
#define DMODEL 1024
#define NBATCH 2
#define MTOT   (NBATCH * NSEQ)          // 4096
#define XN     ((size_t)MTOT * DMODEL)  // 4 Mi elems
#define WN     ((size_t)DMODEL * DMODEL)// 1 Mi elems

__device__ inline u16 f2bf(float f) {
    unsigned int u = __builtin_bit_cast(unsigned int, f);
    unsigned int rounding = 0x7FFFu + ((u >> 16) & 1u);
    return (u16)((u + rounding) >> 16);
}

__device__ inline short8 ld8(const float* p) {
    floatx4 a = *(const floatx4*)p;
    floatx4 b = *(const floatx4*)(p + 4);
    short8 r;
    r[0] = (short)f2bf(a[0]); r[1] = (short)f2bf(a[1]);
    r[2] = (short)f2bf(a[2]); r[3] = (short)f2bf(a[3]);
    r[4] = (short)f2bf(b[0]); r[5] = (short)f2bf(b[1]);
    r[6] = (short)f2bf(b[2]); r[7] = (short)f2bf(b[3]);
    return r;
}
__device__ inline short8 ld8(const u16* p) { return *(const short8*)p; }

// async 16B global->LDS (direct-to-LDS DMA; dest = wave-uniform base + lane*16)
__device__ inline void gl_lds16(const u16* g, short* l) {
    __builtin_amdgcn_global_load_lds(
        (const __attribute__((address_space(1))) unsigned int*)(const void*)g,
        (__attribute__((address_space(3))) unsigned int*)(void*)l, 16, 0, 0);
}

// ---------------------------------------------------------------------------
// fp32 -> bf16 conversion for x, Wq, Wk, Wv, Wo (one pass)
// ---------------------------------------------------------------------------
__global__ __launch_bounds__(256) void cvt_all(const float* __restrict__ x,
                                               const float* __restrict__ wq,
                                               const float* __restrict__ wk,
                                               const float* __restrict__ wv,
                                               const float* __restrict__ wo,
                                               u16* __restrict__ xb,
                                               u16* __restrict__ wqb,
                                               u16* __restrict__ wkb,
                                               u16* __restrict__ wvb,
                                               u16* __restrict__ wob)
{
    size_t t = (size_t)blockIdx.x * 256 + threadIdx.x;
    size_t e = t * 8;
    const float* s; u16* d; size_t off;
    if (e < XN) { s = x; d = xb; off = e; }
    else {
        size_t r = (e - XN) >> 20;              // WN == 2^20
        off = (e - XN) & (WN - 1);
        s = (r == 0) ? wq : (r == 1) ? wk : (r == 2) ? wv : wo;
        d = (r == 0) ? wqb : (r == 1) ? wkb : (r == 2) ? wvb : wob;
    }
    *(short8*)&d[off] = ld8(&s[off]);
}

// ---------------------------------------------------------------------------
// m97-style GEMM: C = A (Mx1024) * B^T (B is Nx1024 row-major), bf16 MFMA.
// 128x128 block tile, BK=64, 4 waves (2x2), 4x4 acc of 16x16 per wave.
// LDS unpadded (global_load_lds needs contiguity); XOR k-chunk swizzle for
// conflict-free ds_read_b128 fragment reads.
// MODE 0: O-projection: C0 = fp32 out + bias. grid (8, 32), B = B0.
// MODE 1: QKV: blockIdx.x<8 -> Q (B0,C0), <16 -> K (B1,C1), else V^T (B2,C2).
// ---------------------------------------------------------------------------
template <int MODE>
__global__ __launch_bounds__(256) void gemm_m97(const u16* __restrict__ A,
                                                const u16* __restrict__ B0,
                                                const u16* __restrict__ B1,
                                                const u16* __restrict__ B2,
                                                const float* __restrict__ bias,
                                                void* __restrict__ C0,
                                                void* __restrict__ C1,
                                                void* __restrict__ C2)
{
    __shared__ __align__(16) short As[128 * 64];
    __shared__ __align__(16) short Bs[128 * 64];

    const int tid  = threadIdx.x;
    const int w    = tid >> 6;
    const int lane = tid & 63;
    const int ln   = lane & 15;
    const int q    = lane >> 4;
    const int lx   = ln & 7;
    const int wm   = w >> 1;
    const int wn   = w & 1;
    const int m0   = blockIdx.y * 128;
    const int widx = (MODE == 1) ? (blockIdx.x >> 3) : 0;
    const int col0 = (MODE == 1) ? ((blockIdx.x & 7) * 128) : (blockIdx.x * 128);
    const u16* Bp  = (MODE == 0) ? B0 : (widx == 0 ? B0 : (widx == 1 ? B1 : B2));

    // staging: lane's chunk position p = lane&7 in row r; fetch global chunk
    // kc = p ^ (r&7)  ->  LDS[r][p] holds global chunk p^(r&7)
    const int rsub = lane >> 3;                      // row-within-8-block
    const int kcl  = (lane & 7) ^ (rsub & 7);        // global k-chunk to fetch

    floatx4 acc[4][4];
#pragma unroll
    for (int i = 0; i < 4; ++i)
#pragma unroll
        for (int j = 0; j < 4; ++j) acc[i][j] = (floatx4){0.f, 0.f, 0.f, 0.f};

    for (int k0 = 0; k0 < DMODEL; k0 += 64) {
#pragma unroll
        for (int i = 0; i < 4; ++i) {
            const int r = (w * 4 + i) * 8 + rsub;    // tile row 0..127
            gl_lds16(&A [(size_t)(m0 + r)   * DMODEL + k0 + kcl * 8], &As[(w * 4 + i) * 512]);
            gl_lds16(&Bp[(size_t)(col0 + r) * DMODEL + k0 + kcl * 8], &Bs[(w * 4 + i) * 512]);
        }
        __syncthreads();
#pragma unroll
        for (int kk = 0; kk < 2; ++kk) {
            short8 af[4], bf[4];
#pragma unroll
            for (int t = 0; t < 4; ++t) {
                af[t] = *(short8*)&As[(wm * 64 + t * 16 + ln) * 64 + (((kk * 4 + q) ^ lx) * 8)];
                bf[t] = *(short8*)&Bs[(wn * 64 + t * 16 + ln) * 64 + (((kk * 4 + q) ^ lx) * 8)];
            }
#pragma unroll
            for (int mt = 0; mt < 4; ++mt)
#pragma unroll
                for (int nt = 0; nt < 4; ++nt)
                    acc[mt][nt] = __builtin_amdgcn_mfma_f32_16x16x32_bf16(af[mt], bf[nt], acc[mt][nt], 0, 0, 0);
        }
        __syncthreads();
    }

    u16* Cw = (MODE == 1) ? (widx == 0 ? (u16*)C0 : (widx == 1 ? (u16*)C1 : (u16*)C2)) : nullptr;
#pragma unroll
    for (int mt = 0; mt < 4; ++mt) {
#pragma unroll
        for (int nt = 0; nt < 4; ++nt) {
            const int coln = wn * 64 + nt * 16 + ln;
            float bval = 0.f;
            if (MODE == 0) bval = bias[col0 + coln];
#pragma unroll
            for (int reg = 0; reg < 4; ++reg) {
                const int grow = m0 + wm * 64 + mt * 16 + q * 4 + reg;
                const float v = acc[mt][nt][reg] + bval;
                if (MODE == 0) {
                    ((float*)C0)[(size_t)grow * DMODEL + col0 + coln] = v;
                } else {
                    const int gcol = col0 + coln;
                    const int h = gcol >> 6, d = gcol & 63;
                    const int b = grow >> 11, tok = grow & 2047;
                    if (widx == 2)
                        Cw[((size_t)(b * NH + h) * DHEAD + d) * NSEQ + tok] = f2bf(v);
                    else
                        Cw[((size_t)(b * NH + h) * NSEQ + tok) * DHEAD + d] = f2bf(v);
                }
            }
        }
    }
}

// ---------------------------------------------------------------------------
// Fallback small-tile GEMM (fp32 staging) — used only if ws too small.
// ---------------------------------------------------------------------------
template <int MODE, typename TA, typename TB>
__global__ __launch_bounds__(256) void gemm_bt(const TA* __restrict__ A,
                                               const TB* __restrict__ B,
                                               const float* __restrict__ bias,
                                               void* __restrict__ Cv)
{
    __shared__ __align__(16) short As[64][72];
    __shared__ __align__(16) short Bs[64][72];

    const int tid  = threadIdx.x;
    const int w    = tid >> 6;
    const int lane = tid & 63;
    const int ln   = lane & 15;
    const int q    = lane >> 4;
    const int wm   = w >> 1;
    const int wn   = w & 1;
    const int m0   = blockIdx.y * 64;
    const int n0   = blockIdx.x * 64;
    const int r    = tid >> 3;
    const int c8   = (tid & 7) * 8;

    floatx4 zero = {0.f, 0.f, 0.f, 0.f};
    floatx4 acc[2][2];
    acc[0][0] = zero; acc[0][1] = zero; acc[1][0] = zero; acc[1][1] = zero;

    for (int k0 = 0; k0 < DMODEL; k0 += 64) {
        *(short8*)&As[r][c8]      = ld8(&A[(size_t)(m0 + r) * DMODEL + k0 + c8]);
        *(short8*)&As[r + 32][c8] = ld8(&A[(size_t)(m0 + r + 32) * DMODEL + k0 + c8]);
        *(short8*)&Bs[r][c8]      = ld8(&B[(size_t)(n0 + r) * DMODEL + k0 + c8]);
        *(short8*)&Bs[r + 32][c8] = ld8(&B[(size_t)(n0 + r + 32) * DMODEL + k0 + c8]);
        __syncthreads();
#pragma unroll
        for (int kk = 0; kk < 2; ++kk) {
            short8 a0 = *(short8*)&As[wm * 32 + ln][kk * 32 + q * 8];
            short8 a1 = *(short8*)&As[wm * 32 + 16 + ln][kk * 32 + q * 8];
            short8 b0 = *(short8*)&Bs[wn * 32 + ln][kk * 32 + q * 8];
            short8 b1 = *(short8*)&Bs[wn * 32 + 16 + ln][kk * 32 + q * 8];
            acc[0][0] = __builtin_amdgcn_mfma_f32_16x16x32_bf16(a0, b0, acc[0][0], 0, 0, 0);
            acc[0][1] = __builtin_amdgcn_mfma_f32_16x16x32_bf16(a0, b1, acc[0][1], 0, 0, 0);
            acc[1][0] = __builtin_amdgcn_mfma_f32_16x16x32_bf16(a1, b0, acc[1][0], 0, 0, 0);
            acc[1][1] = __builtin_amdgcn_mfma_f32_16x16x32_bf16(a1, b1, acc[1][1], 0, 0, 0);
        }
        __syncthreads();
    }

#pragma unroll
    for (int mt = 0; mt < 2; ++mt) {
#pragma unroll
        for (int nt = 0; nt < 2; ++nt) {
            const int coln = wn * 32 + nt * 16 + ln;
            float bval = 0.f;
            if (MODE == 0) bval = bias[n0 + coln];
#pragma unroll
            for (int reg = 0; reg < 4; ++reg) {
                const int grow = m0 + wm * 32 + mt * 16 + q * 4 + reg;
                const float v = acc[mt][nt][reg] + bval;
                if (MODE == 0) {
                    ((float*)Cv)[(size_t)grow * DMODEL + n0 + coln] = v;
                } else {
                    const int b = grow >> 11, tok = grow & 2047, h = n0 >> 6;
                    if (MODE == 1)
                        ((u16*)Cv)[((size_t)(b * NH + h) * NSEQ + tok) * DHEAD + coln] = f2bf(v);
                    else
                        ((u16*)Cv)[((size_t)(b * NH + h) * DHEAD + coln) * NSEQ + tok] = f2bf(v);
                }
            }
        }
    }
}

// ---------------------------------------------------------------------------
// Flash attention: Q [b,h,n,dh], K [b,h,n,dh], Vt [b,h,dh,n] -> O [b,n,h*dh]
// ---------------------------------------------------------------------------
__global__ __launch_bounds__(256) void attn_kernel(const u16* __restrict__ Q,
                                                   const u16* __restrict__ K,
                                                   const u16* __restrict__ Vt,
                                                   u16* __restrict__ O)
{
    __shared__ __align__(16) short Ks[64][72];
    __shared__ __align__(16) short Vs[64][72];
    __shared__ __align__(16) short Ps[4][16][72];

    const int tid  = threadIdx.x;
    const int w    = tid >> 6;
    const int lane = tid & 63;
    const int ln   = lane & 15;
    const int q    = lane >> 4;
    const int bh   = blockIdx.y;
    const int qbase = blockIdx.x * 64;
    const int r    = tid >> 3;
    const int c8   = (tid & 7) * 8;

    const u16* qptr = Q + ((size_t)bh * NSEQ + qbase + w * 16 + ln) * DHEAD;
    short8 aq[2];
    aq[0] = *(const short8*)&qptr[q * 8];
    aq[1] = *(const short8*)&qptr[32 + q * 8];

    floatx4 zero = {0.f, 0.f, 0.f, 0.f};
    floatx4 o[4];
    float mrow[4], lrow[4];
#pragma unroll
    for (int i = 0; i < 4; ++i) { o[i] = zero; mrow[i] = -INFINITY; lrow[i] = 0.f; }

    for (int kt = 0; kt < NSEQ / 64; ++kt) {
        const int kbase = kt * 64;
        *(short8*)&Ks[r][c8]      = *(const short8*)&K[((size_t)bh * NSEQ + kbase + r) * DHEAD + c8];
        *(short8*)&Ks[r + 32][c8] = *(const short8*)&K[((size_t)bh * NSEQ + kbase + r + 32) * DHEAD + c8];
        *(short8*)&Vs[r][c8]      = *(const short8*)&Vt[((size_t)bh * DHEAD + r) * NSEQ + kbase + c8];
        *(short8*)&Vs[r + 32][c8] = *(const short8*)&Vt[((size_t)bh * DHEAD + r + 32) * NSEQ + kbase + c8];
        __syncthreads();

        floatx4 s[4];
#pragma unroll
        for (int t = 0; t < 4; ++t) {
            s[t] = zero;
#pragma unroll
            for (int kk = 0; kk < 2; ++kk) {
                short8 bk = *(short8*)&Ks[t * 16 + ln][kk * 32 + q * 8];
                s[t] = __builtin_amdgcn_mfma_f32_16x16x32_bf16(aq[kk], bk, s[t], 0, 0, 0);
            }
        }

#pragma unroll
        for (int reg = 0; reg < 4; ++reg) {
            float mx = -INFINITY;
#pragma unroll
            for (int t = 0; t < 4; ++t) {
                s[t][reg] *= 0.125f;
                mx = fmaxf(mx, s[t][reg]);
            }
#pragma unroll
            for (int off = 1; off < 16; off <<= 1)
                mx = fmaxf(mx, __shfl_xor(mx, off, 64));
            const float mnew  = fmaxf(mrow[reg], mx);
            const float alpha = __expf(mrow[reg] - mnew);
            float rs = 0.f;
#pragma unroll
            for (int t = 0; t < 4; ++t) {
                float p = __expf(s[t][reg] - mnew);
                s[t][reg] = p;
                rs += p;
            }
#pragma unroll
            for (int off = 1; off < 16; off <<= 1)
                rs += __shfl_xor(rs, off, 64);
            lrow[reg] = lrow[reg] * alpha + rs;
            mrow[reg] = mnew;
#pragma unroll
            for (int t = 0; t < 4; ++t) {
                o[t][reg] *= alpha;
                Ps[w][q * 4 + reg][t * 16 + ln] = (short)f2bf(s[t][reg]);
            }
        }

        short8 pf0 = *(short8*)&Ps[w][ln][q * 8];
        short8 pf1 = *(short8*)&Ps[w][ln][32 + q * 8];
#pragma unroll
        for (int t = 0; t < 4; ++t) {
            short8 bv0 = *(short8*)&Vs[t * 16 + ln][q * 8];
            short8 bv1 = *(short8*)&Vs[t * 16 + ln][32 + q * 8];
            o[t] = __builtin_amdgcn_mfma_f32_16x16x32_bf16(pf0, bv0, o[t], 0, 0, 0);
            o[t] = __builtin_amdgcn_mfma_f32_16x16x32_bf16(pf1, bv1, o[t], 0, 0, 0);
        }
        __syncthreads();
    }

    const int b = bh >> 4, h = bh & 15;
#pragma unroll
    for (int t = 0; t < 4; ++t) {
#pragma unroll
        for (int reg = 0; reg < 4; ++reg) {
            const int tok = qbase + w * 16 + q * 4 + reg;
            const float v = o[t][reg] / lrow[reg];
            O[((size_t)(b * NSEQ + tok)) * DMODEL + h * DHEAD + t * 16 + ln] = f2bf(v);
        }
    }
}

// ---------------------------------------------------------------------------
extern "C" void kernel_launch(void* const* d_in, const int* in_sizes, int n_in,
                              void* d_out, int out_size, void* d_ws, size_t ws_size,
                              hipStream_t stream) {
    (void)in_sizes; (void)n_in; (void)out_size;
    const float* x  = (const float*)d_in[0];
    const float* Wq = (const float*)d_in[1];
    const float* Wk = (const float*)d_in[2];
    const float* Wv = (const float*)d_in[3];
    const float* Wo = (const float*)d_in[4];
    const float* bo = (const float*)d_in[5];
    float* out = (float*)d_out;

    dim3 bb(256);
    dim3 ga(NSEQ / 64, NBATCH * NH);  // attention grid

    const size_t NEED = XN * 2 /*xb/Ob*/ + 4 * WN * 2 /*W*/ + 3 * XN * 2 /*QKVt*/;
    if (ws_size >= NEED) {
        // fast path: bf16 pre-convert + m97-structure GEMMs
        u16* xb  = (u16*)d_ws;                 // 8 MB; Ob aliases after QKV
        u16* Wqb = xb + XN;                    // 2 MB each
        u16* Wkb = Wqb + WN;
        u16* Wvb = Wkb + WN;
        u16* Wob = Wvb + WN;
        u16* Qb  = Wob + WN;                   // 8 MB each
        u16* Kb  = Qb + XN;
        u16* Vtb = Kb + XN;
        u16* Ob  = xb;

        cvt_all<<<dim3((unsigned)((XN + 4 * WN) / 8 / 256)), bb, 0, stream>>>(
            x, Wq, Wk, Wv, Wo, xb, Wqb, Wkb, Wvb, Wob);

        gemm_m97<1><<<dim3(24, 32), bb, 0, stream>>>(xb, Wqb, Wkb, Wvb, nullptr, Qb, Kb, Vtb);
        attn_kernel<<<ga, bb, 0, stream>>>(Qb, Kb, Vtb, Ob);
        gemm_m97<0><<<dim3(8, 32), bb, 0, stream>>>(Ob, Wob, nullptr, nullptr, bo, out, nullptr, nullptr);
    } else {
        // fallback: round-2 path (32 MB workspace)
        u16* Qb  = (u16*)d_ws;
        u16* Kb  = Qb + XN;
        u16* Vtb = Kb + XN;
        u16* Ob  = Vtb + XN;
        dim3 gg(DMODEL / 64, MTOT / 64);
        gemm_bt<1, float, float><<<gg, bb, 0, stream>>>(x, Wq, nullptr, Qb);
        gemm_bt<1, float, float><<<gg, bb, 0, stream>>>(x, Wk, nullptr, Kb);
        gemm_bt<2, float, float><<<gg, bb, 0, stream>>>(x, Wv, nullptr, Vtb);
        attn_kernel<<<ga, bb, 0, stream>>>(Qb, Kb, Vtb, Ob);
        gemm_bt<0, u16, float><<<gg, bb, 0, stream>>>(Ob, Wo, bo, out);
    }
}